// Round 1
// baseline (379.226 us; speedup 1.0000x reference)
//
#include <hip/hip_runtime.h>
#include <math.h>

#define H_IMG 1080
#define W_IMG 1920
#define NPIX (H_IMG * W_IMG)
#define RBLOCKS 2048
#define RTHREADS 256
#define NACC 27

// ---- workspace layout (byte offsets) ----
#define OFF_POSE     0                         // 16 f32
#define OFF_MINMAX   64                        // 2 u32
#define OFF_PARTIALS 256                       // NACC * RBLOCKS doubles = 442368 B
#define OFF_NX       442624                    // NPIX f32
#define OFF_NY       (OFF_NX + NPIX * 4)
#define OFF_NZ       (OFF_NY + NPIX * 4)
#define WS_NEEDED    ((size_t)OFF_NZ + (size_t)NPIX * 4)

__device__ __forceinline__ float clampf(float x, float lo, float hi) {
    return fminf(fmaxf(x, lo), hi);
}

struct F3 { float x, y, z; };

// normal of vertex-map(depth1) at (j,i), Sobel w/ edge padding, invalidated at
// global depth min/max (matches _compute_normal exactly).
__device__ __forceinline__ F3 normal_at(const float* __restrict__ depth1,
                                        int j, int i, float ifx, float ify,
                                        float cx, float cy, float dmin, float dmax) {
    float vx[3][3], vy[3][3], vz[3][3];
#pragma unroll
    for (int dj = 0; dj < 3; dj++) {
        int jj = j + dj - 1; jj = jj < 0 ? 0 : (jj > H_IMG - 1 ? H_IMG - 1 : jj);
#pragma unroll
        for (int di = 0; di < 3; di++) {
            int ii = i + di - 1; ii = ii < 0 ? 0 : (ii > W_IMG - 1 ? W_IMG - 1 : ii);
            float d = depth1[jj * W_IMG + ii];
            vx[dj][di] = ((float)ii - cx) * ifx * d;
            vy[dj][di] = ((float)jj - cy) * ify * d;
            vz[dj][di] = d;
        }
    }
    float dxx = -vx[0][0] + vx[0][2] - 2.f * vx[1][0] + 2.f * vx[1][2] - vx[2][0] + vx[2][2];
    float dxy = -vy[0][0] + vy[0][2] - 2.f * vy[1][0] + 2.f * vy[1][2] - vy[2][0] + vy[2][2];
    float dxz = -vz[0][0] + vz[0][2] - 2.f * vz[1][0] + 2.f * vz[1][2] - vz[2][0] + vz[2][2];
    float dyx = -vx[0][0] - 2.f * vx[0][1] - vx[0][2] + vx[2][0] + 2.f * vx[2][1] + vx[2][2];
    float dyy = -vy[0][0] - 2.f * vy[0][1] - vy[0][2] + vy[2][0] + 2.f * vy[2][1] + vy[2][2];
    float dyz = -vz[0][0] - 2.f * vz[0][1] - vz[0][2] + vz[2][0] + 2.f * vz[2][1] + vz[2][2];
    float nx = dxy * dyz - dxz * dyy;
    float ny = dxz * dyx - dxx * dyz;
    float nz = dxx * dyy - dxy * dyx;
    float inv = 1.f / (sqrtf(nx * nx + ny * ny + nz * nz) + 1e-8f);
    float dc = vz[1][1];
    bool invalid = (dc <= dmin) || (dc >= dmax);
    F3 n;
    n.x = invalid ? 0.f : nx * inv;
    n.y = invalid ? 0.f : ny * inv;
    n.z = invalid ? 0.f : nz * inv;
    return n;
}

__global__ void k_init(const float* __restrict__ pose_in, float* __restrict__ ws_pose,
                       unsigned int* __restrict__ minmax) {
    int t = threadIdx.x;
    if (t < 16) ws_pose[t] = pose_in[t];
    if (t == 16) { minmax[0] = 0x7F800000u; minmax[1] = 0u; }
}

__global__ void k_minmax(const float* __restrict__ d, unsigned int* __restrict__ minmax) {
    int tid = blockIdx.x * blockDim.x + threadIdx.x;
    int stride = gridDim.x * blockDim.x;
    float mn = INFINITY, mx = -INFINITY;
    for (int i = tid; i < NPIX; i += stride) {
        float v = d[i];
        mn = fminf(mn, v);
        mx = fmaxf(mx, v);
    }
    for (int off = 32; off > 0; off >>= 1) {
        mn = fminf(mn, __shfl_down(mn, off));
        mx = fmaxf(mx, __shfl_down(mx, off));
    }
    __shared__ float smn[4], smx[4];
    int lane = threadIdx.x & 63, wid = threadIdx.x >> 6;
    if (lane == 0) { smn[wid] = mn; smx[wid] = mx; }
    __syncthreads();
    if (threadIdx.x == 0) {
        int nw = blockDim.x >> 6;
        for (int w = 1; w < nw; w++) { mn = fminf(mn, smn[w]); mx = fmaxf(mx, smx[w]); }
        // positive floats: uint bit-pattern order == value order
        atomicMin(&minmax[0], __float_as_uint(mn));
        atomicMax(&minmax[1], __float_as_uint(mx));
    }
}

__global__ void k_normal(const float* __restrict__ depth1, const float* __restrict__ Kmat,
                         const unsigned int* __restrict__ minmax,
                         float* __restrict__ nxp, float* __restrict__ nyp,
                         float* __restrict__ nzp) {
    float fx = Kmat[0], cx = Kmat[2], fy = Kmat[4], cy = Kmat[5];
    float ifx = 1.f / fx, ify = 1.f / fy;
    float dmin = __uint_as_float(minmax[0]), dmax = __uint_as_float(minmax[1]);
    int tid0 = blockIdx.x * blockDim.x + threadIdx.x;
    int stride = gridDim.x * blockDim.x;
    for (int idx = tid0; idx < NPIX; idx += stride) {
        int j = idx / W_IMG, i = idx - j * W_IMG;
        F3 n = normal_at(depth1, j, i, ifx, ify, cx, cy, dmin, dmax);
        nxp[idx] = n.x; nyp[idx] = n.y; nzp[idx] = n.z;
    }
}

template <bool USE_NBUF>
__global__ __launch_bounds__(RTHREADS)
void k_resid(const float* __restrict__ depth0, const float* __restrict__ depth1,
             const float* __restrict__ Kmat,
             const float* __restrict__ nxp, const float* __restrict__ nyp,
             const float* __restrict__ nzp,
             const unsigned int* __restrict__ minmax,
             const float* __restrict__ pose, double* __restrict__ partials) {
    float fx = Kmat[0], cx = Kmat[2], fy = Kmat[4], cy = Kmat[5];
    float ifx = 1.f / fx, ify = 1.f / fy;
    float R00 = pose[0], R01 = pose[1], R02 = pose[2],  t0 = pose[3];
    float R10 = pose[4], R11 = pose[5], R12 = pose[6],  t1 = pose[7];
    float R20 = pose[8], R21 = pose[9], R22 = pose[10], t2 = pose[11];
    float dmin = 0.f, dmax = 0.f;
    if (!USE_NBUF) {
        dmin = __uint_as_float(minmax[0]);
        dmax = __uint_as_float(minmax[1]);
    }
    double acc[NACC];
#pragma unroll
    for (int k = 0; k < NACC; k++) acc[k] = 0.0;

    int tid0 = blockIdx.x * blockDim.x + threadIdx.x;
    int stride = gridDim.x * blockDim.x;
    for (int idx = tid0; idx < NPIX; idx += stride) {
        int j = idx / W_IMG;
        int i = idx - j * W_IMG;
        float d0 = depth0[idx];
        float v0x = ((float)i - cx) * ifx * d0;
        float v0y = ((float)j - cy) * ify * d0;
        float v0z = d0;
        float px = R00 * v0x + R01 * v0y + R02 * v0z + t0;
        float py = R10 * v0x + R11 * v0y + R12 * v0z + t1;
        float pz = R20 * v0x + R21 * v0y + R22 * v0z + t2;
        float u, v;
        bool inview;
        if (pz > 1e-6f) {
            u = px / pz * fx + cx;
            v = py / pz * fy + cy;
            inview = (u > 0.f) && (u < (float)(W_IMG - 1)) && (v > 0.f) && (v < (float)(H_IMG - 1));
        } else {
            u = 0.f; v = 0.f; inview = false;
        }
        float uc = clampf(u, 0.f, (float)(W_IMG - 1));
        float vc = clampf(v, 0.f, (float)(H_IMG - 1));
        float x0f = floorf(uc), y0f = floorf(vc);
        int x0 = (int)x0f, y0 = (int)y0f;
        int x1 = min(x0 + 1, W_IMG - 1);
        int y1 = min(y0 + 1, H_IMG - 1);
        float wx = uc - x0f, wy = vc - y0f;
        float w1x = 1.f - wx, w1y = 1.f - wy;
        int i00 = y0 * W_IMG + x0, i01 = y0 * W_IMG + x1;
        int i10 = y1 * W_IMG + x0, i11 = y1 * W_IMG + x1;
        float d00 = depth1[i00], d01 = depth1[i01], d10 = depth1[i10], d11 = depth1[i11];
        float cX0 = ((float)x0 - cx) * ifx, cX1 = ((float)x1 - cx) * ifx;
        float cY0 = ((float)y0 - cy) * ify, cY1 = ((float)y1 - cy) * ify;
        // bilinear warp of vertex1 (two-stage lerp like reference)
        float rvx = (cX0 * d00 * w1x + cX1 * d01 * wx) * w1y + (cX0 * d10 * w1x + cX1 * d11 * wx) * wy;
        float rvy = (cY0 * d00 * w1x + cY0 * d01 * wx) * w1y + (cY1 * d10 * w1x + cY1 * d11 * wx) * wy;
        float rvz = (d00 * w1x + d01 * wx) * w1y + (d10 * w1x + d11 * wx) * wy;
        // bilinear warp of normal1
        float n00x, n00y, n00z, n01x, n01y, n01z, n10x, n10y, n10z, n11x, n11y, n11z;
        if (USE_NBUF) {
            n00x = nxp[i00]; n00y = nyp[i00]; n00z = nzp[i00];
            n01x = nxp[i01]; n01y = nyp[i01]; n01z = nzp[i01];
            n10x = nxp[i10]; n10y = nyp[i10]; n10z = nzp[i10];
            n11x = nxp[i11]; n11y = nyp[i11]; n11z = nzp[i11];
        } else {
            F3 a = normal_at(depth1, y0, x0, ifx, ify, cx, cy, dmin, dmax);
            F3 b = normal_at(depth1, y0, x1, ifx, ify, cx, cy, dmin, dmax);
            F3 c = normal_at(depth1, y1, x0, ifx, ify, cx, cy, dmin, dmax);
            F3 d = normal_at(depth1, y1, x1, ifx, ify, cx, cy, dmin, dmax);
            n00x = a.x; n00y = a.y; n00z = a.z;
            n01x = b.x; n01y = b.y; n01z = b.z;
            n10x = c.x; n10y = c.y; n10z = c.z;
            n11x = d.x; n11y = d.y; n11z = d.z;
        }
        float rnx = (n00x * w1x + n01x * wx) * w1y + (n10x * w1x + n11x * wx) * wy;
        float rny = (n00y * w1x + n01y * wx) * w1y + (n10y * w1x + n11y * wx) * wy;
        float rnz = (n00z * w1x + n01z * wx) * w1y + (n10z * w1x + n11z * wx) * wy;

        bool mask1 = rvz > 0.f;
        float ddx = px - rvx, ddy = py - rvy, ddz = pz - rvz;
        bool occ = (!inview) || (sqrtf(ddx * ddx + ddy * ddy + ddz * ddz) > 0.1f);
        bool bad = occ || !(d0 > 0.f) || (!mask1);
        if (!bad) {
            float res = rnx * ddx + rny * ddy + rnz * ddz;
            float jv[6];
            jv[0] = -(py * rnz - pz * rny);  // -cross(v0to1, n)
            jv[1] = -(pz * rnx - px * rnz);
            jv[2] = -(px * rny - py * rnx);
            jv[3] = -rnx; jv[4] = -rny; jv[5] = -rnz;
            int k = 0;
#pragma unroll
            for (int a = 0; a < 6; a++) {
#pragma unroll
                for (int b = a; b < 6; b++) {
                    acc[k] += (double)jv[a] * (double)jv[b];
                    k++;
                }
            }
#pragma unroll
            for (int a = 0; a < 6; a++) acc[21 + a] += (double)jv[a] * (double)res;
        }
    }

    // deterministic block reduction: wave shfl -> LDS -> per-k sum
    __shared__ double red[RTHREADS / 64][NACC];
    int lane = threadIdx.x & 63, wid = threadIdx.x >> 6;
#pragma unroll
    for (int k = 0; k < NACC; k++) {
        double v = acc[k];
        for (int off = 32; off > 0; off >>= 1) v += __shfl_down(v, off);
        if (lane == 0) red[wid][k] = v;
    }
    __syncthreads();
    if (threadIdx.x < NACC) {
        double s = 0.0;
#pragma unroll
        for (int w = 0; w < RTHREADS / 64; w++) s += red[w][threadIdx.x];
        partials[(size_t)threadIdx.x * RBLOCKS + blockIdx.x] = s;
    }
}

__global__ void k_solve(const double* __restrict__ partials, float* __restrict__ pose,
                        float* __restrict__ pose_out) {
    __shared__ double sw[4];
    __shared__ double ssum[NACC];
    int tid = threadIdx.x;
    int lane = tid & 63, wid = tid >> 6;
    for (int k = 0; k < NACC; k++) {
        double v = 0.0;
        for (int i = tid; i < RBLOCKS; i += 256) v += partials[(size_t)k * RBLOCKS + i];
        for (int off = 32; off > 0; off >>= 1) v += __shfl_down(v, off);
        if (lane == 0) sw[wid] = v;
        __syncthreads();
        if (tid == 0) ssum[k] = sw[0] + sw[1] + sw[2] + sw[3];
        __syncthreads();
    }
    if (tid == 0) {
        double A[6][6], b[6];
        int k = 0;
        for (int a = 0; a < 6; a++)
            for (int c = a; c < 6; c++) {
                double s = ssum[k++];
                A[a][c] = s; A[c][a] = s;
            }
        for (int a = 0; a < 6; a++) b[a] = ssum[21 + a];
        double tr = A[0][0] + A[1][1] + A[2][2] + A[3][3] + A[4][4] + A[5][5];
        for (int a = 0; a < 6; a++) A[a][a] += tr * 0.001;
        // Gauss-Jordan with partial pivoting: solve A x = b
        double M[6][7];
        for (int r = 0; r < 6; r++) {
            for (int c = 0; c < 6; c++) M[r][c] = A[r][c];
            M[r][6] = b[r];
        }
        for (int c = 0; c < 6; c++) {
            int piv = c;
            double best = fabs(M[c][c]);
            for (int r = c + 1; r < 6; r++) {
                double v = fabs(M[r][c]);
                if (v > best) { best = v; piv = r; }
            }
            if (piv != c) {
                for (int q = c; q < 7; q++) { double t = M[c][q]; M[c][q] = M[piv][q]; M[piv][q] = t; }
            }
            double pv = M[c][c];
            for (int r = 0; r < 6; r++) {
                if (r == c) continue;
                double f = M[r][c] / pv;
                for (int q = c; q < 7; q++) M[r][q] -= f * M[c][q];
            }
        }
        double xi[6];
        for (int c = 0; c < 6; c++) xi[c] = M[c][6] / M[c][c];
        // exp_so3
        double w0 = xi[0], w1 = xi[1], w2 = xi[2];
        double th = sqrt(w0 * w0 + w1 * w1 + w2 * w2);
        double dR[3][3] = {{1, 0, 0}, {0, 1, 0}, {0, 0, 1}};
        if (th > 1e-10) {
            double sA = sin(th) / th;
            double sB = (1.0 - cos(th)) / (th * th);
            double wh[3][3] = {{0, -w2, w1}, {w2, 0, -w0}, {-w1, w0, 0}};
            double wh2[3][3];
            for (int r = 0; r < 3; r++)
                for (int cc = 0; cc < 3; cc++) {
                    double s = 0;
                    for (int m = 0; m < 3; m++) s += wh[r][m] * wh[m][cc];
                    wh2[r][cc] = s;
                }
            for (int r = 0; r < 3; r++)
                for (int cc = 0; cc < 3; cc++)
                    dR[r][cc] = (r == cc ? 1.0 : 0.0) + sA * wh[r][cc] + sB * wh2[r][cc];
        }
        double R[3][3], t[3];
        for (int r = 0; r < 3; r++) {
            for (int cc = 0; cc < 3; cc++) R[r][cc] = pose[r * 4 + cc];
            t[r] = pose[r * 4 + 3];
        }
        double Rn[3][3], tn[3];
        for (int r = 0; r < 3; r++) {
            for (int cc = 0; cc < 3; cc++) {
                double s = 0;
                for (int m = 0; m < 3; m++) s += dR[r][m] * R[m][cc];
                Rn[r][cc] = s;
            }
            tn[r] = dR[r][0] * t[0] + dR[r][1] * t[1] + dR[r][2] * t[2] + xi[3 + r];
        }
        for (int r = 0; r < 3; r++) {
            for (int cc = 0; cc < 3; cc++) pose[r * 4 + cc] = (float)Rn[r][cc];
            pose[r * 4 + 3] = (float)tn[r];
        }
        for (int q = 0; q < 16; q++) pose_out[q] = pose[q];
    }
}

extern "C" void kernel_launch(void* const* d_in, const int* in_sizes, int n_in,
                              void* d_out, int out_size, void* d_ws, size_t ws_size,
                              hipStream_t stream) {
    const float* pose_in = (const float*)d_in[0];
    const float* depth0 = (const float*)d_in[1];
    const float* depth1 = (const float*)d_in[2];
    const float* K = (const float*)d_in[3];
    float* out = (float*)d_out;
    char* ws = (char*)d_ws;
    float* ws_pose = (float*)(ws + OFF_POSE);
    unsigned int* minmax = (unsigned int*)(ws + OFF_MINMAX);
    double* partials = (double*)(ws + OFF_PARTIALS);
    bool use_nbuf = ws_size >= WS_NEEDED;
    float* nxp = nullptr;
    float* nyp = nullptr;
    float* nzp = nullptr;
    if (use_nbuf) {
        nxp = (float*)(ws + OFF_NX);
        nyp = (float*)(ws + OFF_NY);
        nzp = (float*)(ws + OFF_NZ);
    }

    k_init<<<1, 64, 0, stream>>>(pose_in, ws_pose, minmax);
    k_minmax<<<1024, 256, 0, stream>>>(depth1, minmax);
    if (use_nbuf)
        k_normal<<<2048, 256, 0, stream>>>(depth1, K, minmax, nxp, nyp, nzp);
    for (int it = 0; it < 3; ++it) {
        if (use_nbuf)
            k_resid<true><<<RBLOCKS, RTHREADS, 0, stream>>>(depth0, depth1, K, nxp, nyp, nzp,
                                                            minmax, ws_pose, partials);
        else
            k_resid<false><<<RBLOCKS, RTHREADS, 0, stream>>>(depth0, depth1, K, nullptr, nullptr,
                                                             nullptr, minmax, ws_pose, partials);
        k_solve<<<1, 256, 0, stream>>>(partials, ws_pose, out);
    }
}

// Round 2
// 222.637 us; speedup vs baseline: 1.7033x; 1.7033x over previous
//
#include <hip/hip_runtime.h>
#include <math.h>

#define H_IMG 1080
#define W_IMG 1920
#define NPIX (H_IMG * W_IMG)
#define RBLOCKS 2048
#define RTHREADS 256
#define NACC 27

// ---- workspace layout (byte offsets) ----
#define OFF_POSE     0                         // 16 f32
#define OFF_MINMAX   64                        // 2 u32
#define OFF_SUMS     128                       // NACC f64 = 216 B
#define OFF_PARTIALS 512                       // NACC * RBLOCKS f64 = 442368 B
#define OFF_ND       442880                    // NPIX float4 (nx,ny,nz,depth1) = 33177600 B
#define WS_NEEDED    ((size_t)OFF_ND + (size_t)NPIX * 16)

__device__ __forceinline__ float clampf(float x, float lo, float hi) {
    return fminf(fmaxf(x, lo), hi);
}

struct F3 { float x, y, z; };

// normal of vertex-map(depth1) at (j,i), Sobel w/ edge padding, invalidated at
// global depth min/max (matches _compute_normal exactly).
__device__ __forceinline__ F3 normal_at(const float* __restrict__ depth1,
                                        int j, int i, float ifx, float ify,
                                        float cx, float cy, float dmin, float dmax) {
    float vx[3][3], vy[3][3], vz[3][3];
#pragma unroll
    for (int dj = 0; dj < 3; dj++) {
        int jj = j + dj - 1; jj = jj < 0 ? 0 : (jj > H_IMG - 1 ? H_IMG - 1 : jj);
#pragma unroll
        for (int di = 0; di < 3; di++) {
            int ii = i + di - 1; ii = ii < 0 ? 0 : (ii > W_IMG - 1 ? W_IMG - 1 : ii);
            float d = depth1[jj * W_IMG + ii];
            vx[dj][di] = ((float)ii - cx) * ifx * d;
            vy[dj][di] = ((float)jj - cy) * ify * d;
            vz[dj][di] = d;
        }
    }
    float dxx = -vx[0][0] + vx[0][2] - 2.f * vx[1][0] + 2.f * vx[1][2] - vx[2][0] + vx[2][2];
    float dxy = -vy[0][0] + vy[0][2] - 2.f * vy[1][0] + 2.f * vy[1][2] - vy[2][0] + vy[2][2];
    float dxz = -vz[0][0] + vz[0][2] - 2.f * vz[1][0] + 2.f * vz[1][2] - vz[2][0] + vz[2][2];
    float dyx = -vx[0][0] - 2.f * vx[0][1] - vx[0][2] + vx[2][0] + 2.f * vx[2][1] + vx[2][2];
    float dyy = -vy[0][0] - 2.f * vy[0][1] - vy[0][2] + vy[2][0] + 2.f * vy[2][1] + vy[2][2];
    float dyz = -vz[0][0] - 2.f * vz[0][1] - vz[0][2] + vz[2][0] + 2.f * vz[2][1] + vz[2][2];
    float nx = dxy * dyz - dxz * dyy;
    float ny = dxz * dyx - dxx * dyz;
    float nz = dxx * dyy - dxy * dyx;
    float inv = 1.f / (sqrtf(nx * nx + ny * ny + nz * nz) + 1e-8f);
    float dc = vz[1][1];
    bool invalid = (dc <= dmin) || (dc >= dmax);
    F3 n;
    n.x = invalid ? 0.f : nx * inv;
    n.y = invalid ? 0.f : ny * inv;
    n.z = invalid ? 0.f : nz * inv;
    return n;
}

__global__ void k_init(const float* __restrict__ pose_in, float* __restrict__ ws_pose,
                       unsigned int* __restrict__ minmax) {
    int t = threadIdx.x;
    if (t < 16) ws_pose[t] = pose_in[t];
    if (t == 16) { minmax[0] = 0x7F800000u; minmax[1] = 0u; }
}

__global__ void k_minmax(const float* __restrict__ d, unsigned int* __restrict__ minmax) {
    int tid = blockIdx.x * blockDim.x + threadIdx.x;
    int stride = gridDim.x * blockDim.x;
    float mn = INFINITY, mx = -INFINITY;
    for (int i = tid; i < NPIX; i += stride) {
        float v = d[i];
        mn = fminf(mn, v);
        mx = fmaxf(mx, v);
    }
    for (int off = 32; off > 0; off >>= 1) {
        mn = fminf(mn, __shfl_down(mn, off));
        mx = fmaxf(mx, __shfl_down(mx, off));
    }
    __shared__ float smn[4], smx[4];
    int lane = threadIdx.x & 63, wid = threadIdx.x >> 6;
    if (lane == 0) { smn[wid] = mn; smx[wid] = mx; }
    __syncthreads();
    if (threadIdx.x == 0) {
        int nw = blockDim.x >> 6;
        for (int w = 1; w < nw; w++) { mn = fminf(mn, smn[w]); mx = fmaxf(mx, smx[w]); }
        // positive floats: uint bit-pattern order == value order
        atomicMin(&minmax[0], __float_as_uint(mn));
        atomicMax(&minmax[1], __float_as_uint(mx));
    }
}

// writes packed (nx, ny, nz, depth1) per pixel
__global__ void k_normal(const float* __restrict__ depth1, const float* __restrict__ Kmat,
                         const unsigned int* __restrict__ minmax,
                         float4* __restrict__ nd) {
    float fx = Kmat[0], cx = Kmat[2], fy = Kmat[4], cy = Kmat[5];
    float ifx = 1.f / fx, ify = 1.f / fy;
    float dmin = __uint_as_float(minmax[0]), dmax = __uint_as_float(minmax[1]);
    int tid0 = blockIdx.x * blockDim.x + threadIdx.x;
    int stride = gridDim.x * blockDim.x;
    for (int idx = tid0; idx < NPIX; idx += stride) {
        int j = idx / W_IMG, i = idx - j * W_IMG;
        F3 n = normal_at(depth1, j, i, ifx, ify, cx, cy, dmin, dmax);
        float4 o; o.x = n.x; o.y = n.y; o.z = n.z; o.w = depth1[idx];
        nd[idx] = o;
    }
}

template <bool USE_NBUF>
__global__ __launch_bounds__(RTHREADS)
void k_resid(const float* __restrict__ depth0, const float* __restrict__ depth1,
             const float* __restrict__ Kmat,
             const float4* __restrict__ nd,
             const unsigned int* __restrict__ minmax,
             const float* __restrict__ pose, double* __restrict__ partials) {
    float fx = Kmat[0], cx = Kmat[2], fy = Kmat[4], cy = Kmat[5];
    float ifx = 1.f / fx, ify = 1.f / fy;
    float R00 = pose[0], R01 = pose[1], R02 = pose[2],  t0 = pose[3];
    float R10 = pose[4], R11 = pose[5], R12 = pose[6],  t1 = pose[7];
    float R20 = pose[8], R21 = pose[9], R22 = pose[10], t2 = pose[11];
    float dmin = 0.f, dmax = 0.f;
    if (!USE_NBUF) {
        dmin = __uint_as_float(minmax[0]);
        dmax = __uint_as_float(minmax[1]);
    }
    // per-thread f32 accumulators (only ~4 pixels/thread -> rounding negligible;
    // f64 from the block stage onward)
    float acc[NACC];
#pragma unroll
    for (int k = 0; k < NACC; k++) acc[k] = 0.f;

    int tid0 = blockIdx.x * blockDim.x + threadIdx.x;
    int stride = gridDim.x * blockDim.x;
    for (int idx = tid0; idx < NPIX; idx += stride) {
        int j = idx / W_IMG;
        int i = idx - j * W_IMG;
        float d0 = depth0[idx];
        float v0x = ((float)i - cx) * ifx * d0;
        float v0y = ((float)j - cy) * ify * d0;
        float v0z = d0;
        float px = R00 * v0x + R01 * v0y + R02 * v0z + t0;
        float py = R10 * v0x + R11 * v0y + R12 * v0z + t1;
        float pz = R20 * v0x + R21 * v0y + R22 * v0z + t2;
        float u, v;
        bool inview;
        if (pz > 1e-6f) {
            float rz = 1.f / pz;
            u = px * rz * fx + cx;
            v = py * rz * fy + cy;
            inview = (u > 0.f) && (u < (float)(W_IMG - 1)) && (v > 0.f) && (v < (float)(H_IMG - 1));
        } else {
            u = 0.f; v = 0.f; inview = false;
        }
        float uc = clampf(u, 0.f, (float)(W_IMG - 1));
        float vc = clampf(v, 0.f, (float)(H_IMG - 1));
        float x0f = floorf(uc), y0f = floorf(vc);
        int x0 = (int)x0f, y0 = (int)y0f;
        int x1 = min(x0 + 1, W_IMG - 1);
        int y1 = min(y0 + 1, H_IMG - 1);
        float wx = uc - x0f, wy = vc - y0f;
        float w1x = 1.f - wx, w1y = 1.f - wy;
        int i00 = y0 * W_IMG + x0, i01 = y0 * W_IMG + x1;
        int i10 = y1 * W_IMG + x0, i11 = y1 * W_IMG + x1;
        float d00, d01, d10, d11;
        float n00x, n00y, n00z, n01x, n01y, n01z, n10x, n10y, n10z, n11x, n11y, n11z;
        if (USE_NBUF) {
            float4 c00 = nd[i00], c01 = nd[i01], c10 = nd[i10], c11 = nd[i11];
            d00 = c00.w; d01 = c01.w; d10 = c10.w; d11 = c11.w;
            n00x = c00.x; n00y = c00.y; n00z = c00.z;
            n01x = c01.x; n01y = c01.y; n01z = c01.z;
            n10x = c10.x; n10y = c10.y; n10z = c10.z;
            n11x = c11.x; n11y = c11.y; n11z = c11.z;
        } else {
            d00 = depth1[i00]; d01 = depth1[i01]; d10 = depth1[i10]; d11 = depth1[i11];
            F3 a = normal_at(depth1, y0, x0, ifx, ify, cx, cy, dmin, dmax);
            F3 b = normal_at(depth1, y0, x1, ifx, ify, cx, cy, dmin, dmax);
            F3 c = normal_at(depth1, y1, x0, ifx, ify, cx, cy, dmin, dmax);
            F3 d = normal_at(depth1, y1, x1, ifx, ify, cx, cy, dmin, dmax);
            n00x = a.x; n00y = a.y; n00z = a.z;
            n01x = b.x; n01y = b.y; n01z = b.z;
            n10x = c.x; n10y = c.y; n10z = c.z;
            n11x = d.x; n11y = d.y; n11z = d.z;
        }
        float cX0 = ((float)x0 - cx) * ifx, cX1 = ((float)x1 - cx) * ifx;
        float cY0 = ((float)y0 - cy) * ify, cY1 = ((float)y1 - cy) * ify;
        // bilinear warp of vertex1
        float rvx = (cX0 * d00 * w1x + cX1 * d01 * wx) * w1y + (cX0 * d10 * w1x + cX1 * d11 * wx) * wy;
        float rvy = (cY0 * d00 * w1x + cY0 * d01 * wx) * w1y + (cY1 * d10 * w1x + cY1 * d11 * wx) * wy;
        float rvz = (d00 * w1x + d01 * wx) * w1y + (d10 * w1x + d11 * wx) * wy;
        // bilinear warp of normal1
        float rnx = (n00x * w1x + n01x * wx) * w1y + (n10x * w1x + n11x * wx) * wy;
        float rny = (n00y * w1x + n01y * wx) * w1y + (n10y * w1x + n11y * wx) * wy;
        float rnz = (n00z * w1x + n01z * wx) * w1y + (n10z * w1x + n11z * wx) * wy;

        bool mask1 = rvz > 0.f;
        float ddx = px - rvx, ddy = py - rvy, ddz = pz - rvz;
        bool occ = (!inview) || (sqrtf(ddx * ddx + ddy * ddy + ddz * ddz) > 0.1f);
        bool bad = occ || !(d0 > 0.f) || (!mask1);
        if (!bad) {
            float res = rnx * ddx + rny * ddy + rnz * ddz;
            float jv[6];
            jv[0] = -(py * rnz - pz * rny);  // -cross(v0to1, n)
            jv[1] = -(pz * rnx - px * rnz);
            jv[2] = -(px * rny - py * rnx);
            jv[3] = -rnx; jv[4] = -rny; jv[5] = -rnz;
            int k = 0;
#pragma unroll
            for (int a = 0; a < 6; a++) {
#pragma unroll
                for (int b = a; b < 6; b++) {
                    acc[k] += jv[a] * jv[b];
                    k++;
                }
            }
#pragma unroll
            for (int a = 0; a < 6; a++) acc[21 + a] += jv[a] * res;
        }
    }

    // deterministic block reduction in f64: wave shfl -> LDS -> per-k sum
    __shared__ double red[RTHREADS / 64][NACC];
    int lane = threadIdx.x & 63, wid = threadIdx.x >> 6;
#pragma unroll
    for (int k = 0; k < NACC; k++) {
        double v = (double)acc[k];
        for (int off = 32; off > 0; off >>= 1) v += __shfl_down(v, off);
        if (lane == 0) red[wid][k] = v;
    }
    __syncthreads();
    if (threadIdx.x < NACC) {
        double s = 0.0;
#pragma unroll
        for (int w = 0; w < RTHREADS / 64; w++) s += red[w][threadIdx.x];
        partials[(size_t)threadIdx.x * RBLOCKS + blockIdx.x] = s;
    }
}

// one block per accumulator k: coalesced parallel reduction of 2048 partials
__global__ void k_reduce(const double* __restrict__ partials, double* __restrict__ sums) {
    int k = blockIdx.x;
    double v = 0.0;
    for (int i = threadIdx.x; i < RBLOCKS; i += 256) v += partials[(size_t)k * RBLOCKS + i];
    for (int off = 32; off > 0; off >>= 1) v += __shfl_down(v, off);
    __shared__ double sw[4];
    int lane = threadIdx.x & 63, wid = threadIdx.x >> 6;
    if (lane == 0) sw[wid] = v;
    __syncthreads();
    if (threadIdx.x == 0) sums[k] = sw[0] + sw[1] + sw[2] + sw[3];
}

__global__ void k_solve(const double* __restrict__ sums, float* __restrict__ pose,
                        float* __restrict__ pose_out) {
    __shared__ double ssum[NACC];
    int tid = threadIdx.x;
    if (tid < NACC) ssum[tid] = sums[tid];   // 27 parallel loads
    __syncthreads();
    if (tid == 0) {
        double A[6][6], b[6];
        int k = 0;
        for (int a = 0; a < 6; a++)
            for (int c = a; c < 6; c++) {
                double s = ssum[k++];
                A[a][c] = s; A[c][a] = s;
            }
        for (int a = 0; a < 6; a++) b[a] = ssum[21 + a];
        double tr = A[0][0] + A[1][1] + A[2][2] + A[3][3] + A[4][4] + A[5][5];
        for (int a = 0; a < 6; a++) A[a][a] += tr * 0.001;
        // Gauss-Jordan with partial pivoting: solve A x = b
        double M[6][7];
        for (int r = 0; r < 6; r++) {
            for (int c = 0; c < 6; c++) M[r][c] = A[r][c];
            M[r][6] = b[r];
        }
        for (int c = 0; c < 6; c++) {
            int piv = c;
            double best = fabs(M[c][c]);
            for (int r = c + 1; r < 6; r++) {
                double v = fabs(M[r][c]);
                if (v > best) { best = v; piv = r; }
            }
            if (piv != c) {
                for (int q = c; q < 7; q++) { double t = M[c][q]; M[c][q] = M[piv][q]; M[piv][q] = t; }
            }
            double pv = M[c][c];
            for (int r = 0; r < 6; r++) {
                if (r == c) continue;
                double f = M[r][c] / pv;
                for (int q = c; q < 7; q++) M[r][q] -= f * M[c][q];
            }
        }
        double xi[6];
        for (int c = 0; c < 6; c++) xi[c] = M[c][6] / M[c][c];
        // exp_so3
        double w0 = xi[0], w1 = xi[1], w2 = xi[2];
        double th = sqrt(w0 * w0 + w1 * w1 + w2 * w2);
        double dR[3][3] = {{1, 0, 0}, {0, 1, 0}, {0, 0, 1}};
        if (th > 1e-10) {
            double sA = sin(th) / th;
            double sB = (1.0 - cos(th)) / (th * th);
            double wh[3][3] = {{0, -w2, w1}, {w2, 0, -w0}, {-w1, w0, 0}};
            double wh2[3][3];
            for (int r = 0; r < 3; r++)
                for (int cc = 0; cc < 3; cc++) {
                    double s = 0;
                    for (int m = 0; m < 3; m++) s += wh[r][m] * wh[m][cc];
                    wh2[r][cc] = s;
                }
            for (int r = 0; r < 3; r++)
                for (int cc = 0; cc < 3; cc++)
                    dR[r][cc] = (r == cc ? 1.0 : 0.0) + sA * wh[r][cc] + sB * wh2[r][cc];
        }
        double R[3][3], t[3];
        for (int r = 0; r < 3; r++) {
            for (int cc = 0; cc < 3; cc++) R[r][cc] = pose[r * 4 + cc];
            t[r] = pose[r * 4 + 3];
        }
        double Rn[3][3], tn[3];
        for (int r = 0; r < 3; r++) {
            for (int cc = 0; cc < 3; cc++) {
                double s = 0;
                for (int m = 0; m < 3; m++) s += dR[r][m] * R[m][cc];
                Rn[r][cc] = s;
            }
            tn[r] = dR[r][0] * t[0] + dR[r][1] * t[1] + dR[r][2] * t[2] + xi[3 + r];
        }
        for (int r = 0; r < 3; r++) {
            for (int cc = 0; cc < 3; cc++) pose[r * 4 + cc] = (float)Rn[r][cc];
            pose[r * 4 + 3] = (float)tn[r];
        }
        for (int q = 0; q < 16; q++) pose_out[q] = pose[q];
    }
}

extern "C" void kernel_launch(void* const* d_in, const int* in_sizes, int n_in,
                              void* d_out, int out_size, void* d_ws, size_t ws_size,
                              hipStream_t stream) {
    const float* pose_in = (const float*)d_in[0];
    const float* depth0 = (const float*)d_in[1];
    const float* depth1 = (const float*)d_in[2];
    const float* K = (const float*)d_in[3];
    float* out = (float*)d_out;
    char* ws = (char*)d_ws;
    float* ws_pose = (float*)(ws + OFF_POSE);
    unsigned int* minmax = (unsigned int*)(ws + OFF_MINMAX);
    double* sums = (double*)(ws + OFF_SUMS);
    double* partials = (double*)(ws + OFF_PARTIALS);
    bool use_nbuf = ws_size >= WS_NEEDED;
    float4* nd = use_nbuf ? (float4*)(ws + OFF_ND) : nullptr;

    k_init<<<1, 64, 0, stream>>>(pose_in, ws_pose, minmax);
    k_minmax<<<1024, 256, 0, stream>>>(depth1, minmax);
    if (use_nbuf)
        k_normal<<<2048, 256, 0, stream>>>(depth1, K, minmax, nd);
    for (int it = 0; it < 3; ++it) {
        if (use_nbuf)
            k_resid<true><<<RBLOCKS, RTHREADS, 0, stream>>>(depth0, depth1, K, nd,
                                                            minmax, ws_pose, partials);
        else
            k_resid<false><<<RBLOCKS, RTHREADS, 0, stream>>>(depth0, depth1, K, nullptr,
                                                             minmax, ws_pose, partials);
        k_reduce<<<NACC, 256, 0, stream>>>(partials, sums);
        k_solve<<<1, 64, 0, stream>>>(sums, ws_pose, out);
    }
}

// Round 3
// 197.447 us; speedup vs baseline: 1.9207x; 1.1276x over previous
//
#include <hip/hip_runtime.h>
#include <math.h>

#define H_IMG 1080
#define W_IMG 1920
#define NPIX (H_IMG * W_IMG)
#define W4 480                                 // W_IMG / 4
#define QUADS (NPIX / 4)                       // 518400
#define RB 2025                                // QUADS / 256, exact
#define NACC 27

// ---- workspace layout (byte offsets) ----
#define OFF_POSE     0                         // 16 f32
#define OFF_MINMAX   64                        // 2 u32
#define OFF_SUMS     128                       // NACC f64 = 216 B
#define OFF_PARTIALS 512                       // NACC * RB f64 = 437400 B
#define OFF_ND       442880                    // NPIX float4 (nx,ny,nz,depth1)
#define WS_NEEDED    ((size_t)OFF_ND + (size_t)NPIX * 16)

__device__ __forceinline__ float clampf(float x, float lo, float hi) {
    return fminf(fmaxf(x, lo), hi);
}

struct F3 { float x, y, z; };

__device__ __forceinline__ F3 normal_at(const float* __restrict__ depth1,
                                        int j, int i, float ifx, float ify,
                                        float cx, float cy, float dmin, float dmax) {
    float vx[3][3], vy[3][3], vz[3][3];
#pragma unroll
    for (int dj = 0; dj < 3; dj++) {
        int jj = j + dj - 1; jj = jj < 0 ? 0 : (jj > H_IMG - 1 ? H_IMG - 1 : jj);
#pragma unroll
        for (int di = 0; di < 3; di++) {
            int ii = i + di - 1; ii = ii < 0 ? 0 : (ii > W_IMG - 1 ? W_IMG - 1 : ii);
            float d = depth1[jj * W_IMG + ii];
            vx[dj][di] = ((float)ii - cx) * ifx * d;
            vy[dj][di] = ((float)jj - cy) * ify * d;
            vz[dj][di] = d;
        }
    }
    float dxx = -vx[0][0] + vx[0][2] - 2.f * vx[1][0] + 2.f * vx[1][2] - vx[2][0] + vx[2][2];
    float dxy = -vy[0][0] + vy[0][2] - 2.f * vy[1][0] + 2.f * vy[1][2] - vy[2][0] + vy[2][2];
    float dxz = -vz[0][0] + vz[0][2] - 2.f * vz[1][0] + 2.f * vz[1][2] - vz[2][0] + vz[2][2];
    float dyx = -vx[0][0] - 2.f * vx[0][1] - vx[0][2] + vx[2][0] + 2.f * vx[2][1] + vx[2][2];
    float dyy = -vy[0][0] - 2.f * vy[0][1] - vy[0][2] + vy[2][0] + 2.f * vy[2][1] + vy[2][2];
    float dyz = -vz[0][0] - 2.f * vz[0][1] - vz[0][2] + vz[2][0] + 2.f * vz[2][1] + vz[2][2];
    float nx = dxy * dyz - dxz * dyy;
    float ny = dxz * dyx - dxx * dyz;
    float nz = dxx * dyy - dxy * dyx;
    float inv = 1.f / (sqrtf(nx * nx + ny * ny + nz * nz) + 1e-8f);
    float dc = vz[1][1];
    bool invalid = (dc <= dmin) || (dc >= dmax);
    F3 n;
    n.x = invalid ? 0.f : nx * inv;
    n.y = invalid ? 0.f : ny * inv;
    n.z = invalid ? 0.f : nz * inv;
    return n;
}

__global__ void k_init(const float* __restrict__ pose_in, float* __restrict__ ws_pose,
                       unsigned int* __restrict__ minmax) {
    int t = threadIdx.x;
    if (t < 16) ws_pose[t] = pose_in[t];
    if (t == 16) { minmax[0] = 0x7F800000u; minmax[1] = 0u; }
}

__global__ void k_minmax(const float4* __restrict__ dq, unsigned int* __restrict__ minmax) {
    int tid = blockIdx.x * blockDim.x + threadIdx.x;
    int stride = gridDim.x * blockDim.x;
    float mn = INFINITY, mx = -INFINITY;
    for (int i = tid; i < QUADS; i += stride) {
        float4 v = dq[i];
        mn = fminf(mn, fminf(fminf(v.x, v.y), fminf(v.z, v.w)));
        mx = fmaxf(mx, fmaxf(fmaxf(v.x, v.y), fmaxf(v.z, v.w)));
    }
    for (int off = 32; off > 0; off >>= 1) {
        mn = fminf(mn, __shfl_down(mn, off));
        mx = fmaxf(mx, __shfl_down(mx, off));
    }
    __shared__ float smn[4], smx[4];
    int lane = threadIdx.x & 63, wid = threadIdx.x >> 6;
    if (lane == 0) { smn[wid] = mn; smx[wid] = mx; }
    __syncthreads();
    if (threadIdx.x == 0) {
        int nw = blockDim.x >> 6;
        for (int w = 1; w < nw; w++) { mn = fminf(mn, smn[w]); mx = fmaxf(mx, smx[w]); }
        atomicMin(&minmax[0], __float_as_uint(mn));  // positive floats: bit order == value order
        atomicMax(&minmax[1], __float_as_uint(mx));
    }
}

// 4 consecutive pixels per thread; writes packed (nx, ny, nz, depth1)
__global__ __launch_bounds__(256)
void k_normal(const float* __restrict__ depth1, const float* __restrict__ Kmat,
              const unsigned int* __restrict__ minmax, float4* __restrict__ nd) {
    int qid = blockIdx.x * 256 + threadIdx.x;
    if (qid >= QUADS) return;
    float fx = Kmat[0], cx = Kmat[2], fy = Kmat[4], cy = Kmat[5];
    float ifx = 1.f / fx, ify = 1.f / fy;
    float dmin = __uint_as_float(minmax[0]), dmax = __uint_as_float(minmax[1]);
    int j = qid / W4;
    int i0 = (qid - j * W4) * 4;
    int rows[3];
    rows[0] = j > 0 ? j - 1 : 0;
    rows[1] = j;
    rows[2] = j < H_IMG - 1 ? j + 1 : H_IMG - 1;
    int il = i0 > 0 ? i0 - 1 : 0;
    int ir = i0 + 4 < W_IMG ? i0 + 4 : W_IMG - 1;
    float d[3][6];
#pragma unroll
    for (int r = 0; r < 3; r++) {
        const float* rp = depth1 + rows[r] * W_IMG;
        float4 m = *reinterpret_cast<const float4*>(rp + i0);
        d[r][0] = rp[il]; d[r][1] = m.x; d[r][2] = m.y; d[r][3] = m.z; d[r][4] = m.w; d[r][5] = rp[ir];
    }
    float colc[6], rowc[3];
#pragma unroll
    for (int c = 0; c < 6; c++) {
        int col = i0 - 1 + c; col = col < 0 ? 0 : (col > W_IMG - 1 ? W_IMG - 1 : col);
        colc[c] = ((float)col - cx) * ifx;
    }
#pragma unroll
    for (int r = 0; r < 3; r++) rowc[r] = ((float)rows[r] - cy) * ify;
    float vx[3][6], vy[3][6];
#pragma unroll
    for (int r = 0; r < 3; r++)
#pragma unroll
        for (int c = 0; c < 6; c++) { vx[r][c] = colc[c] * d[r][c]; vy[r][c] = rowc[r] * d[r][c]; }
    float4 out[4];
#pragma unroll
    for (int p = 0; p < 4; p++) {
        int a = p, b = p + 1, e = p + 2;
        float dxx = -vx[0][a] + vx[0][e] - 2.f * vx[1][a] + 2.f * vx[1][e] - vx[2][a] + vx[2][e];
        float dxy = -vy[0][a] + vy[0][e] - 2.f * vy[1][a] + 2.f * vy[1][e] - vy[2][a] + vy[2][e];
        float dxz = -d[0][a] + d[0][e] - 2.f * d[1][a] + 2.f * d[1][e] - d[2][a] + d[2][e];
        float dyx = -vx[0][a] - 2.f * vx[0][b] - vx[0][e] + vx[2][a] + 2.f * vx[2][b] + vx[2][e];
        float dyy = -vy[0][a] - 2.f * vy[0][b] - vy[0][e] + vy[2][a] + 2.f * vy[2][b] + vy[2][e];
        float dyz = -d[0][a] - 2.f * d[0][b] - d[0][e] + d[2][a] + 2.f * d[2][b] + d[2][e];
        float nx = dxy * dyz - dxz * dyy;
        float ny = dxz * dyx - dxx * dyz;
        float nz = dxx * dyy - dxy * dyx;
        float inv = 1.f / (sqrtf(nx * nx + ny * ny + nz * nz) + 1e-8f);
        float dc = d[1][b];
        bool invalid = (dc <= dmin) || (dc >= dmax);
        out[p].x = invalid ? 0.f : nx * inv;
        out[p].y = invalid ? 0.f : ny * inv;
        out[p].z = invalid ? 0.f : nz * inv;
        out[p].w = dc;
    }
    float4* dst = nd + (size_t)j * W_IMG + i0;
#pragma unroll
    for (int p = 0; p < 4; p++) dst[p] = out[p];
}

template <bool USE_NBUF>
__global__ __launch_bounds__(256)
void k_resid(const float4* __restrict__ depth0q, const float* __restrict__ depth1,
             const float* __restrict__ Kmat, const float4* __restrict__ nd,
             const unsigned int* __restrict__ minmax,
             const float* __restrict__ pose, double* __restrict__ partials) {
    float fx = Kmat[0], cx = Kmat[2], fy = Kmat[4], cy = Kmat[5];
    float ifx = 1.f / fx, ify = 1.f / fy;
    float R00 = pose[0], R01 = pose[1], R02 = pose[2],  t0 = pose[3];
    float R10 = pose[4], R11 = pose[5], R12 = pose[6],  t1 = pose[7];
    float R20 = pose[8], R21 = pose[9], R22 = pose[10], t2 = pose[11];
    float dmin = 0.f, dmax = 0.f;
    if (!USE_NBUF) {
        dmin = __uint_as_float(minmax[0]);
        dmax = __uint_as_float(minmax[1]);
    }
    float acc[NACC];
#pragma unroll
    for (int k = 0; k < NACC; k++) acc[k] = 0.f;

    int tid = threadIdx.x;
    int qid = blockIdx.x * 256 + tid;          // grid is exactly RB*256 == QUADS
    int j = qid / W4;
    int i0 = (qid - j * W4) * 4;
    float jf = (float)j;
    float4 d4 = depth0q[qid];
    float d0s[4] = {d4.x, d4.y, d4.z, d4.w};

#pragma unroll
    for (int pp = 0; pp < 2; pp++) {
        float px[2], py[2], pz[2], wx[2], wy[2];
        int x0[2], x1[2], y0[2], y1[2];
        bool inview[2];
        float d0v[2];
#pragma unroll
        for (int q = 0; q < 2; q++) {
            int p = pp * 2 + q;
            float d0 = d0s[p];
            d0v[q] = d0;
            float v0x = ((float)(i0 + p) - cx) * ifx * d0;
            float v0y = (jf - cy) * ify * d0;
            float X = R00 * v0x + R01 * v0y + R02 * d0 + t0;
            float Y = R10 * v0x + R11 * v0y + R12 * d0 + t1;
            float Z = R20 * v0x + R21 * v0y + R22 * d0 + t2;
            float u, v; bool iv;
            if (Z > 1e-6f) {
                float rz = 1.f / Z;
                u = X * rz * fx + cx;
                v = Y * rz * fy + cy;
                iv = (u > 0.f) && (u < (float)(W_IMG - 1)) && (v > 0.f) && (v < (float)(H_IMG - 1));
            } else { u = 0.f; v = 0.f; iv = false; }
            float uc = clampf(u, 0.f, (float)(W_IMG - 1));
            float vc = clampf(v, 0.f, (float)(H_IMG - 1));
            float x0f = floorf(uc), y0f = floorf(vc);
            x0[q] = (int)x0f; y0[q] = (int)y0f;
            x1[q] = min(x0[q] + 1, W_IMG - 1);
            y1[q] = min(y0[q] + 1, H_IMG - 1);
            wx[q] = uc - x0f; wy[q] = vc - y0f;
            px[q] = X; py[q] = Y; pz[q] = Z; inview[q] = iv;
        }
        // issue all 8 gathers together (MLP)
        float4 c00[2], c01[2], c10[2], c11[2];
        if (USE_NBUF) {
#pragma unroll
            for (int q = 0; q < 2; q++) {
                int i00 = y0[q] * W_IMG + x0[q], i01 = y0[q] * W_IMG + x1[q];
                int i10 = y1[q] * W_IMG + x0[q], i11 = y1[q] * W_IMG + x1[q];
                c00[q] = nd[i00]; c01[q] = nd[i01]; c10[q] = nd[i10]; c11[q] = nd[i11];
            }
        } else {
#pragma unroll
            for (int q = 0; q < 2; q++) {
                F3 a = normal_at(depth1, y0[q], x0[q], ifx, ify, cx, cy, dmin, dmax);
                F3 b = normal_at(depth1, y0[q], x1[q], ifx, ify, cx, cy, dmin, dmax);
                F3 c = normal_at(depth1, y1[q], x0[q], ifx, ify, cx, cy, dmin, dmax);
                F3 e = normal_at(depth1, y1[q], x1[q], ifx, ify, cx, cy, dmin, dmax);
                c00[q].x = a.x; c00[q].y = a.y; c00[q].z = a.z; c00[q].w = depth1[y0[q] * W_IMG + x0[q]];
                c01[q].x = b.x; c01[q].y = b.y; c01[q].z = b.z; c01[q].w = depth1[y0[q] * W_IMG + x1[q]];
                c10[q].x = c.x; c10[q].y = c.y; c10[q].z = c.z; c10[q].w = depth1[y1[q] * W_IMG + x0[q]];
                c11[q].x = e.x; c11[q].y = e.y; c11[q].z = e.z; c11[q].w = depth1[y1[q] * W_IMG + x1[q]];
            }
        }
#pragma unroll
        for (int q = 0; q < 2; q++) {
            float w1x = 1.f - wx[q], w1y = 1.f - wy[q];
            float d00 = c00[q].w, d01 = c01[q].w, d10 = c10[q].w, d11 = c11[q].w;
            float cX0 = ((float)x0[q] - cx) * ifx, cX1 = ((float)x1[q] - cx) * ifx;
            float cY0 = ((float)y0[q] - cy) * ify, cY1 = ((float)y1[q] - cy) * ify;
            float rvx = (cX0 * d00 * w1x + cX1 * d01 * wx[q]) * w1y + (cX0 * d10 * w1x + cX1 * d11 * wx[q]) * wy[q];
            float rvy = (cY0 * d00 * w1x + cY0 * d01 * wx[q]) * w1y + (cY1 * d10 * w1x + cY1 * d11 * wx[q]) * wy[q];
            float rvz = (d00 * w1x + d01 * wx[q]) * w1y + (d10 * w1x + d11 * wx[q]) * wy[q];
            float rnx = (c00[q].x * w1x + c01[q].x * wx[q]) * w1y + (c10[q].x * w1x + c11[q].x * wx[q]) * wy[q];
            float rny = (c00[q].y * w1x + c01[q].y * wx[q]) * w1y + (c10[q].y * w1x + c11[q].y * wx[q]) * wy[q];
            float rnz = (c00[q].z * w1x + c01[q].z * wx[q]) * w1y + (c10[q].z * w1x + c11[q].z * wx[q]) * wy[q];
            bool mask1 = rvz > 0.f;
            float ddx = px[q] - rvx, ddy = py[q] - rvy, ddz = pz[q] - rvz;
            bool occ = (!inview[q]) || (sqrtf(ddx * ddx + ddy * ddy + ddz * ddz) > 0.1f);
            bool bad = occ || !(d0v[q] > 0.f) || (!mask1);
            if (!bad) {
                float res = rnx * ddx + rny * ddy + rnz * ddz;
                float jv[6];
                jv[0] = -(py[q] * rnz - pz[q] * rny);
                jv[1] = -(pz[q] * rnx - px[q] * rnz);
                jv[2] = -(px[q] * rny - py[q] * rnx);
                jv[3] = -rnx; jv[4] = -rny; jv[5] = -rnz;
                int k = 0;
#pragma unroll
                for (int a = 0; a < 6; a++)
#pragma unroll
                    for (int b = a; b < 6; b++) { acc[k] += jv[a] * jv[b]; k++; }
#pragma unroll
                for (int a = 0; a < 6; a++) acc[21 + a] += jv[a] * res;
            }
        }
    }

    // block reduction: LDS transpose (no shfl chains)
    __shared__ float lds[NACC][260];           // 260 pad: rows offset by 4 banks
    __shared__ float part2[NACC][8];
#pragma unroll
    for (int k = 0; k < NACC; k++) lds[k][tid] = acc[k];
    __syncthreads();
    if (tid < NACC * 8) {
        int k = tid >> 3, seg = tid & 7;
        const float4* row = reinterpret_cast<const float4*>(&lds[k][seg * 32]);
        float s = 0.f;
#pragma unroll
        for (int m = 0; m < 8; m++) { float4 v = row[m]; s += v.x + v.y + v.z + v.w; }
        part2[k][seg] = s;
    }
    __syncthreads();
    if (tid < NACC) {
        double s = 0.0;
#pragma unroll
        for (int m = 0; m < 8; m++) s += (double)part2[tid][m];
        partials[(size_t)tid * RB + blockIdx.x] = s;
    }
}

// one block per accumulator k: coalesced parallel reduction of RB partials
__global__ void k_reduce(const double* __restrict__ partials, double* __restrict__ sums) {
    int k = blockIdx.x;
    double v = 0.0;
    for (int i = threadIdx.x; i < RB; i += 256) v += partials[(size_t)k * RB + i];
    for (int off = 32; off > 0; off >>= 1) v += __shfl_down(v, off);
    __shared__ double sw[4];
    int lane = threadIdx.x & 63, wid = threadIdx.x >> 6;
    if (lane == 0) sw[wid] = v;
    __syncthreads();
    if (threadIdx.x == 0) sums[k] = sw[0] + sw[1] + sw[2] + sw[3];
}

__global__ void k_solve(const double* __restrict__ sums, float* __restrict__ pose,
                        float* __restrict__ pose_out) {
    __shared__ double ssum[NACC];
    int tid = threadIdx.x;
    if (tid < NACC) ssum[tid] = sums[tid];
    __syncthreads();
    if (tid == 0) {
        double A[6][6], b[6];
        int k = 0;
        for (int a = 0; a < 6; a++)
            for (int c = a; c < 6; c++) {
                double s = ssum[k++];
                A[a][c] = s; A[c][a] = s;
            }
        for (int a = 0; a < 6; a++) b[a] = ssum[21 + a];
        double tr = A[0][0] + A[1][1] + A[2][2] + A[3][3] + A[4][4] + A[5][5];
        for (int a = 0; a < 6; a++) A[a][a] += tr * 0.001;
        double M[6][7];
        for (int r = 0; r < 6; r++) {
            for (int c = 0; c < 6; c++) M[r][c] = A[r][c];
            M[r][6] = b[r];
        }
        for (int c = 0; c < 6; c++) {
            int piv = c;
            double best = fabs(M[c][c]);
            for (int r = c + 1; r < 6; r++) {
                double v = fabs(M[r][c]);
                if (v > best) { best = v; piv = r; }
            }
            if (piv != c)
                for (int q = c; q < 7; q++) { double t = M[c][q]; M[c][q] = M[piv][q]; M[piv][q] = t; }
            double pv = M[c][c];
            for (int r = 0; r < 6; r++) {
                if (r == c) continue;
                double f = M[r][c] / pv;
                for (int q = c; q < 7; q++) M[r][q] -= f * M[c][q];
            }
        }
        double xi[6];
        for (int c = 0; c < 6; c++) xi[c] = M[c][6] / M[c][c];
        double w0 = xi[0], w1 = xi[1], w2 = xi[2];
        double th = sqrt(w0 * w0 + w1 * w1 + w2 * w2);
        double dR[3][3] = {{1, 0, 0}, {0, 1, 0}, {0, 0, 1}};
        if (th > 1e-10) {
            double sA = sin(th) / th;
            double sB = (1.0 - cos(th)) / (th * th);
            double wh[3][3] = {{0, -w2, w1}, {w2, 0, -w0}, {-w1, w0, 0}};
            double wh2[3][3];
            for (int r = 0; r < 3; r++)
                for (int cc = 0; cc < 3; cc++) {
                    double s = 0;
                    for (int m = 0; m < 3; m++) s += wh[r][m] * wh[m][cc];
                    wh2[r][cc] = s;
                }
            for (int r = 0; r < 3; r++)
                for (int cc = 0; cc < 3; cc++)
                    dR[r][cc] = (r == cc ? 1.0 : 0.0) + sA * wh[r][cc] + sB * wh2[r][cc];
        }
        double R[3][3], t[3];
        for (int r = 0; r < 3; r++) {
            for (int cc = 0; cc < 3; cc++) R[r][cc] = pose[r * 4 + cc];
            t[r] = pose[r * 4 + 3];
        }
        double Rn[3][3], tn[3];
        for (int r = 0; r < 3; r++) {
            for (int cc = 0; cc < 3; cc++) {
                double s = 0;
                for (int m = 0; m < 3; m++) s += dR[r][m] * R[m][cc];
                Rn[r][cc] = s;
            }
            tn[r] = dR[r][0] * t[0] + dR[r][1] * t[1] + dR[r][2] * t[2] + xi[3 + r];
        }
        for (int r = 0; r < 3; r++) {
            for (int cc = 0; cc < 3; cc++) pose[r * 4 + cc] = (float)Rn[r][cc];
            pose[r * 4 + 3] = (float)tn[r];
        }
        for (int q = 0; q < 16; q++) pose_out[q] = pose[q];
    }
}

extern "C" void kernel_launch(void* const* d_in, const int* in_sizes, int n_in,
                              void* d_out, int out_size, void* d_ws, size_t ws_size,
                              hipStream_t stream) {
    const float* pose_in = (const float*)d_in[0];
    const float* depth0 = (const float*)d_in[1];
    const float* depth1 = (const float*)d_in[2];
    const float* K = (const float*)d_in[3];
    float* out = (float*)d_out;
    char* ws = (char*)d_ws;
    float* ws_pose = (float*)(ws + OFF_POSE);
    unsigned int* minmax = (unsigned int*)(ws + OFF_MINMAX);
    double* sums = (double*)(ws + OFF_SUMS);
    double* partials = (double*)(ws + OFF_PARTIALS);
    bool use_nbuf = ws_size >= WS_NEEDED;
    float4* nd = use_nbuf ? (float4*)(ws + OFF_ND) : nullptr;

    k_init<<<1, 64, 0, stream>>>(pose_in, ws_pose, minmax);
    k_minmax<<<1024, 256, 0, stream>>>((const float4*)depth1, minmax);
    if (use_nbuf)
        k_normal<<<RB, 256, 0, stream>>>(depth1, K, minmax, nd);
    for (int it = 0; it < 3; ++it) {
        if (use_nbuf)
            k_resid<true><<<RB, 256, 0, stream>>>((const float4*)depth0, depth1, K, nd,
                                                  minmax, ws_pose, partials);
        else
            k_resid<false><<<RB, 256, 0, stream>>>((const float4*)depth0, depth1, K, nullptr,
                                                   minmax, ws_pose, partials);
        k_reduce<<<NACC, 256, 0, stream>>>(partials, sums);
        k_solve<<<1, 64, 0, stream>>>(sums, ws_pose, out);
    }
}